// Round 15
// baseline (161.514 us; speedup 1.0000x reference)
//
#include <hip/hip_runtime.h>
#include <hip/hip_cooperative_groups.h>

// Deformable conv (K=3, stride=1, pad=1, dil=1), N=8, Cin=Cout=128, H=W=64.
// v16: SINGLE cooperative mega-kernel (grid 256 x 512thr, 1 block/CU co-resident).
//   15 variants all land in the 103-113us band: fused is latency-bound (MfmaUtil 6%,
//   VALU 20%, HBM 5%) and structural attacks are exhausted; the remaining
//   deterministic term is the 2-dispatch structure (prep_all kernel + gap ~10-13us).
//   - stage 0: each block converts its 576-elem share of wt2 (verified layout).
//   - stage 1: each block transposes x-rows (n=bid&7, y=2hp, 2hp+1) via LDS tile
//     (unioned with samp buffer).
//   - grid.sync()  [cooperative launch -- harness-supported]
//   - stage 2: TWO sequential rows of v11's verified fused body (best measured,
//     102.7us): C++ gather chain (compiler-pipelined) -> stash[9][8] regs ->
//     dbuf LDS -> per-tap 16x16x32 MFMA, verified wt2 fragment path + D-layout.
//   Per-CU serial work identical to v11 (512 blocks ran 2-deep per CU anyway);
//   delta = -1 dispatch, -1 gap, prep overlapped.
// ws: xt 8MB @0; wt2 288KB @8388608. Fully rewritten each launch.

#define H  64
#define W  64
#define CIN 128
#define COUT 128
#define NB 8
#define KK 9
#define SROW (CIN + 8)

typedef short bf16x8 __attribute__((ext_vector_type(8)));
typedef float f32x4  __attribute__((ext_vector_type(4)));

namespace cg = cooperative_groups;

__device__ __forceinline__ unsigned short f2bf(float f) {
    unsigned u = __builtin_bit_cast(unsigned, f);
    u += 0x7FFFu + ((u >> 16) & 1u);          // round-nearest-even
    return (unsigned short)(u >> 16);
}
__device__ __forceinline__ unsigned cvt_pk_bf16(float lo, float hi) {
    unsigned r;
    asm("v_cvt_pk_bf16_f32 %0, %1, %2" : "=v"(r) : "v"(lo), "v"(hi));
    return r;                                  // low16 = bf16(lo), high16 = bf16(hi), RNE
}
__device__ __forceinline__ float lo_f(unsigned u) { return __builtin_bit_cast(float, u << 16); }
__device__ __forceinline__ float hi_f(unsigned u) { return __builtin_bit_cast(float, u & 0xFFFF0000u); }

struct GatherCtx {
    const unsigned short *c00, *c01, *c10, *c11;
    float w00, w01, w10, w11;
};

__device__ __forceinline__ GatherCtx gather_setup(float dy, float dx, int ho, int wo, int kk,
                                                  const unsigned short* xbase) {
    GatherCtx g;
    float py = (float)(ho - 1 + kk / 3) + dy;
    float px = (float)(wo - 1 + kk % 3) + dx;
    float y0f = floorf(py), x0f = floorf(px);
    float wy1 = py - y0f, wx1 = px - x0f;
    float wy0 = 1.f - wy1, wx0 = 1.f - wx1;
    int y0 = (int)y0f, x0 = (int)x0f;
    int y1 = y0 + 1, x1 = x0 + 1;
    bool vy0 = (unsigned)y0 < (unsigned)H, vy1 = (unsigned)y1 < (unsigned)H;
    bool vx0 = (unsigned)x0 < (unsigned)W, vx1 = (unsigned)x1 < (unsigned)W;
    g.w00 = (vy0 && vx0) ? wy0 * wx0 : 0.f;
    g.w01 = (vy0 && vx1) ? wy0 * wx1 : 0.f;
    g.w10 = (vy1 && vx0) ? wy1 * wx0 : 0.f;
    g.w11 = (vy1 && vx1) ? wy1 * wx1 : 0.f;
    int yc0 = min(max(y0, 0), H - 1), yc1 = min(max(y1, 0), H - 1);
    int xc0 = min(max(x0, 0), W - 1), xc1 = min(max(x1, 0), W - 1);
    const unsigned short* r0 = xbase + (size_t)yc0 * W * CIN;
    const unsigned short* r1 = xbase + (size_t)yc1 * W * CIN;
    g.c00 = r0 + xc0 * CIN;  g.c01 = r0 + xc1 * CIN;
    g.c10 = r1 + xc0 * CIN;  g.c11 = r1 + xc1 * CIN;
    return g;
}

// One block per (n, ho-pair): n = bid&7 (XCD-local), hp = bid>>3. 512 threads = 8 waves.
__global__ __launch_bounds__(512, 2) void mega(
        const float* __restrict__ x, const float* __restrict__ w,
        const float* __restrict__ offs, unsigned short* __restrict__ xt,
        unsigned short* __restrict__ wt, float* __restrict__ out) {
    // 34,816B LDS, unioned: fp32 transpose tile [128][68] <-> samp[2][64][SROW] bf16
    __shared__ __attribute__((aligned(16))) char ldsbuf[34816];

    int bid = blockIdx.x;
    int n = bid & 7, hp = bid >> 3;
    int t = threadIdx.x;

    // ---- stage 0: weight fp32 [co][c][kk] -> wt2 fragment-contiguous (verified) ----
    {
        int base = bid * 576;                 // 147456 / 256
        #pragma unroll
        for (int k2 = 0; k2 < 2; ++k2) {
            int k = k2 * 512 + t;
            if (k < 576) {
                int idx = base + k;
                int e  = idx & 7;
                int lq = (idx >> 3) & 3;
                int lm = (idx >> 5) & 15;
                int ct = (idx >> 9) & 3;
                int nt = (idx >> 11) & 1;
                int c4 = (idx >> 12) & 3;
                int kk = idx >> 14;
                int co = (c4 << 5) + (nt << 4) + lm;
                int ch = (ct << 5) + (lq << 3) + e;
                wt[idx] = f2bf(w[(co * CIN + ch) * KK + kk]);
            }
        }
    }

    // ---- stage 1: transpose x rows (n, 2hp) and (n, 2hp+1) -> xt (NHWC bf16) ----
    {
        float (*tile)[W + 4] = (float(*)[W + 4])ldsbuf;
        #pragma unroll
        for (int j = 0; j < 2; ++j) {
            int y = (hp << 1) + j;
            const float* src = x + ((size_t)n * CIN * H + y) * W;
            __syncthreads();                  // tile reuse guard
            #pragma unroll
            for (int it = 0; it < 4; ++it) {
                int idx = it * 512 + t;       // 0..2047 float4s
                int c  = idx >> 4;
                int x4 = (idx & 15) << 2;
                int xs = (x4 + ((c >> 5) << 4)) & 63;   // rotate-swizzle per 32-ch group
                *(float4*)&tile[c][xs] = *(const float4*)(src + (size_t)c * H * W + x4);
            }
            __syncthreads();
            int xp  = t >> 3;                 // x position 0..63
            int cbc = (t & 7) << 4;           // 16-ch chunk
            int xr  = (xp + ((cbc >> 5) << 4)) & 63;
            unsigned short* dst = xt + (((size_t)(n * H + y) * W + xp) * CIN + cbc);
            unsigned rr[8];
            #pragma unroll
            for (int i = 0; i < 8; ++i)
                rr[i] = cvt_pk_bf16(tile[cbc + 2 * i][xr], tile[cbc + 2 * i + 1][xr]);
            *(uint4*)(dst)     = make_uint4(rr[0], rr[1], rr[2], rr[3]);
            *(uint4*)(dst + 8) = make_uint4(rr[4], rr[5], rr[6], rr[7]);
        }
    }

    cg::this_grid().sync();                   // xt + wt2 visible grid-wide

    // ---- stage 2: two rows of the v11-verified fused body ----
    int lane = t & 63, wv = t >> 6;
    int lm = lane & 15, lq = lane >> 4;
    int pos = t >> 3;
    int cb  = (t & 7) << 4;
    int slot = (lm << 2) + lq;
    // wave wv covers co block wv*16: wt2 base (tap*8 + wv)*2048 + slot*8; frag ct at +ct*512
    const unsigned short* wvbase = wt + ((size_t)wv << 11) + (slot << 3);
    unsigned short (*samp)[64][SROW] = (unsigned short(*)[64][SROW])ldsbuf;

    const unsigned short* xb = xt + (size_t)n * H * W * CIN + cb;

    #pragma unroll
    for (int j = 0; j < 2; ++j) {
        int ho = (hp << 1) + j;

        // phase A: C++ gather chain (compiler-pipelined) -> stash regs
        const float* offp = offs + (size_t)(n * 2 * KK) * H * W + (size_t)ho * W + pos;
        unsigned stash[KK][8];                // 72 VGPR, statically indexed
        #pragma unroll
        for (int tap = 0; tap < KK; ++tap) {
            float dy = offp[(size_t)(2 * tap) * H * W];
            float dx = offp[(size_t)(2 * tap + 1) * H * W];
            GatherCtx g = gather_setup(dy, dx, ho, pos, tap, xb);
            uint4 gv[8];
            #pragma unroll
            for (int jj = 0; jj < 2; ++jj) {
                gv[4*jj+0] = *(const uint4*)(g.c00 + 8*jj);
                gv[4*jj+1] = *(const uint4*)(g.c01 + 8*jj);
                gv[4*jj+2] = *(const uint4*)(g.c10 + 8*jj);
                gv[4*jj+3] = *(const uint4*)(g.c11 + 8*jj);
            }
            #pragma unroll
            for (int jj = 0; jj < 2; ++jj) {
                const unsigned* a0 = (const unsigned*)&gv[4*jj+0];
                const unsigned* a1 = (const unsigned*)&gv[4*jj+1];
                const unsigned* a2 = (const unsigned*)&gv[4*jj+2];
                const unsigned* a3 = (const unsigned*)&gv[4*jj+3];
                #pragma unroll
                for (int i = 0; i < 4; ++i) {
                    float v0 = g.w00*lo_f(a0[i]) + g.w01*lo_f(a1[i]) + g.w10*lo_f(a2[i]) + g.w11*lo_f(a3[i]);
                    float v1 = g.w00*hi_f(a0[i]) + g.w01*hi_f(a1[i]) + g.w10*hi_f(a2[i]) + g.w11*hi_f(a3[i]);
                    stash[tap][4*jj+i] = cvt_pk_bf16(v0, v1);
                }
            }
        }

        // phase B: 8 waves, wave = 64 pos x 16 co; dbuf LDS; per-tap barrier (v11)
        f32x4 acc[4];
        #pragma unroll
        for (int mt = 0; mt < 4; ++mt) acc[mt] = f32x4{0.f, 0.f, 0.f, 0.f};

        if (j == 0) __syncthreads();          // tile (stage-1) reads done grid-wide? local: guard union reuse
        {
            unsigned short* ld = &samp[0][pos][cb];
            *(uint4*)(ld)     = make_uint4(stash[0][0], stash[0][1], stash[0][2], stash[0][3]);
            *(uint4*)(ld + 8) = make_uint4(stash[0][4], stash[0][5], stash[0][6], stash[0][7]);
        }
        __syncthreads();

        #pragma unroll
        for (int tap = 0; tap < KK; ++tap) {
            if (tap < KK - 1) {               // stage tap+1 into the other buffer
                unsigned short* ld = &samp[(tap + 1) & 1][pos][cb];
                *(uint4*)(ld)     = make_uint4(stash[tap+1][0], stash[tap+1][1],
                                               stash[tap+1][2], stash[tap+1][3]);
                *(uint4*)(ld + 8) = make_uint4(stash[tap+1][4], stash[tap+1][5],
                                               stash[tap+1][6], stash[tap+1][7]);
            }
            const unsigned short* wkb = wvbase + ((size_t)(tap << 3) << 11);
            bf16x8 bW[4];
            #pragma unroll
            for (int ct = 0; ct < 4; ++ct)
                bW[ct] = *(const bf16x8*)(wkb + (ct << 9));

            __builtin_amdgcn_s_setprio(1);
            #pragma unroll
            for (int ct = 0; ct < 4; ++ct) {
                bf16x8 a[4];
                #pragma unroll
                for (int mt = 0; mt < 4; ++mt)
                    a[mt] = *(const bf16x8*)&samp[tap & 1][lm + (mt << 4)][(ct << 5) + (lq << 3)];
                #pragma unroll
                for (int mt = 0; mt < 4; ++mt)
                    acc[mt] = __builtin_amdgcn_mfma_f32_16x16x32_bf16(a[mt], bW[ct], acc[mt], 0, 0, 0);
            }
            __builtin_amdgcn_s_setprio(0);
            __syncthreads();
        }

        // epilogue: D[m = mt*16 + lq*4 + jj][col = lm] -> out[n][co][ho][wo]
        int co = (wv << 4) + lm;
        #pragma unroll
        for (int mt = 0; mt < 4; ++mt) {
            int wob = (mt << 4) + (lq << 2);
            *(f32x4*)(out + (((size_t)(n * COUT + co) * H + ho) * W + wob)) = acc[mt];
        }
    }
}

extern "C" void kernel_launch(void* const* d_in, const int* in_sizes, int n_in,
                              void* d_out, int out_size, void* d_ws, size_t ws_size,
                              hipStream_t stream) {
    const float* x      = (const float*)d_in[0];   // (8,128,64,64)
    const float* offset = (const float*)d_in[1];   // (8,18,64,64)
    const float* weight = (const float*)d_in[2];   // (128,128,3,3)
    float* out = (float*)d_out;

    unsigned short* xt = (unsigned short*)d_ws;                                  // 8 MB
    unsigned short* wt = (unsigned short*)((char*)d_ws + 8388608);               // 288 KB

    const float* xa = x; const float* wa = weight; const float* oa = offset;
    unsigned short* xta = xt; unsigned short* wta = wt; float* outa = out;
    void* args[] = { (void*)&xa, (void*)&wa, (void*)&oa,
                     (void*)&xta, (void*)&wta, (void*)&outa };
    hipLaunchCooperativeKernel((const void*)mega, dim3(NB * H / 2), dim3(512),
                               args, 0, stream);
}

// Round 16
// 107.262 us; speedup vs baseline: 1.5058x; 1.5058x over previous
//
#include <hip/hip_runtime.h>

// Deformable conv (K=3, stride=1, pad=1, dil=1), N=8, Cin=Cout=128, H=W=64.
// v17 = EXACT v11 (best measured: 102.7us) + one tweak: all 18 dy/dx offset loads
//   hoisted to the top of phase A (plain C++, 18 VGPR) so each tap's gather-address
//   chain doesn't start with a fresh ~200cyc L2 load. Everything else byte-identical:
//   - phase A: barrier-free 9-tap C++ gather chain (compiler-pipelined; asm/DRAIN
//     variants measured slower) -> stash[9][8] regs (72 VGPR, static idx).
//   - phase B: 8 waves, wave = 64 pos x 16 co; dbuf LDS samp[2][64][SROW]=34.8KB;
//     one barrier/tap; B-frags from verified fragment-contiguous wt2; setprio(1)
//     around MFMA cluster; verified D-layout epilogue.
//   - launch_bounds(512,2): 256-VGPR budget, 1 block/CU, 2 serial blocks.
//   - XCD-local n=bid&7 (all blocks of image n on XCD n; FETCH 41.6->6.5MB).
// ws: xt 8MB @0; wt2 288KB @8388608. Fully rewritten each launch.

#define H  64
#define W  64
#define CIN 128
#define COUT 128
#define NB 8
#define KK 9
#define SROW (CIN + 8)

typedef short bf16x8 __attribute__((ext_vector_type(8)));
typedef float f32x4  __attribute__((ext_vector_type(4)));

__device__ __forceinline__ unsigned short f2bf(float f) {
    unsigned u = __builtin_bit_cast(unsigned, f);
    u += 0x7FFFu + ((u >> 16) & 1u);          // round-nearest-even
    return (unsigned short)(u >> 16);
}
__device__ __forceinline__ unsigned cvt_pk_bf16(float lo, float hi) {
    unsigned r;
    asm("v_cvt_pk_bf16_f32 %0, %1, %2" : "=v"(r) : "v"(lo), "v"(hi));
    return r;                                  // low16 = bf16(lo), high16 = bf16(hi), RNE
}
__device__ __forceinline__ float lo_f(unsigned u) { return __builtin_bit_cast(float, u << 16); }
__device__ __forceinline__ float hi_f(unsigned u) { return __builtin_bit_cast(float, u & 0xFFFF0000u); }

// Merged prep: blocks [0, NB*H) transpose x (NCHW fp32 -> NHWC bf16), XCD-local (n = b&7);
// blocks [NB*H, NB*H+576): weight fp32 [co][c][kk] -> wt2 fragment-contiguous bf16:
//   wt2 flat idx = ((((kk*4 + c4)*2 + nt)*4 + ct)*64 + lm*4 + lq)*8 + e
//   where co = c4*32 + nt*16 + lm, ch = ct*32 + lq*8 + e.   [verified rounds 6-15]
__global__ void prep_all(const float* __restrict__ x, const float* __restrict__ w,
                         unsigned short* __restrict__ xt, unsigned short* __restrict__ wt) {
    int b = blockIdx.x;
    int t = threadIdx.x;
    if (b >= NB * H) {                        // ---- weight part ----
        int idx = (b - NB * H) * 256 + t;
        if (idx < KK * COUT * CIN) {
            int e  = idx & 7;
            int lq = (idx >> 3) & 3;
            int lm = (idx >> 5) & 15;
            int ct = (idx >> 9) & 3;
            int nt = (idx >> 11) & 1;
            int c4 = (idx >> 12) & 3;
            int kk = idx >> 14;
            int co = (c4 << 5) + (nt << 4) + lm;
            int ch = (ct << 5) + (lq << 3) + e;
            wt[idx] = f2bf(w[(co * CIN + ch) * KK + kk]);
        }
        return;
    }
    // ---- x-transpose part: one (n,y) row per block; n = b&7 matches XCD map ----
    __shared__ float tile[CIN][W + 4];
    int n = b & 7, y = b >> 3;
    const float* src = x + ((size_t)n * CIN * H + y) * W;
    #pragma unroll
    for (int it = 0; it < 8; ++it) {
        int idx = it * 256 + t;               // 0..2047 float4s
        int c  = idx >> 4;
        int x4 = (idx & 15) << 2;
        int xs = (x4 + ((c >> 5) << 4)) & 63; // rotate-swizzle per 32-ch group
        *(float4*)&tile[c][xs] = *(const float4*)(src + (size_t)c * H * W + x4);
    }
    __syncthreads();
    int xp = t >> 2;                          // x position 0..63
    int cbch = (t & 3) << 5;                  // channel base (32-ch chunk)
    int xr = (xp + ((cbch >> 5) << 4)) & 63;
    unsigned short* dst = xt + (((size_t)(n * H + y) * W + xp) * CIN + cbch);
    unsigned rr[16];
    #pragma unroll
    for (int i = 0; i < 16; ++i)
        rr[i] = cvt_pk_bf16(tile[cbch + 2 * i][xr], tile[cbch + 2 * i + 1][xr]);
    #pragma unroll
    for (int i = 0; i < 4; ++i)
        ((uint4*)dst)[i] = make_uint4(rr[4*i], rr[4*i+1], rr[4*i+2], rr[4*i+3]);
}

struct GatherCtx {
    const unsigned short *c00, *c01, *c10, *c11;
    float w00, w01, w10, w11;
};

__device__ __forceinline__ GatherCtx gather_setup(float dy, float dx, int ho, int wo, int kk,
                                                  const unsigned short* xbase) {
    GatherCtx g;
    float py = (float)(ho - 1 + kk / 3) + dy;
    float px = (float)(wo - 1 + kk % 3) + dx;
    float y0f = floorf(py), x0f = floorf(px);
    float wy1 = py - y0f, wx1 = px - x0f;
    float wy0 = 1.f - wy1, wx0 = 1.f - wx1;
    int y0 = (int)y0f, x0 = (int)x0f;
    int y1 = y0 + 1, x1 = x0 + 1;
    bool vy0 = (unsigned)y0 < (unsigned)H, vy1 = (unsigned)y1 < (unsigned)H;
    bool vx0 = (unsigned)x0 < (unsigned)W, vx1 = (unsigned)x1 < (unsigned)W;
    g.w00 = (vy0 && vx0) ? wy0 * wx0 : 0.f;
    g.w01 = (vy0 && vx1) ? wy0 * wx1 : 0.f;
    g.w10 = (vy1 && vx0) ? wy1 * wx0 : 0.f;
    g.w11 = (vy1 && vx1) ? wy1 * wx1 : 0.f;
    int yc0 = min(max(y0, 0), H - 1), yc1 = min(max(y1, 0), H - 1);
    int xc0 = min(max(x0, 0), W - 1), xc1 = min(max(x1, 0), W - 1);
    const unsigned short* r0 = xbase + (size_t)yc0 * W * CIN;
    const unsigned short* r1 = xbase + (size_t)yc1 * W * CIN;
    g.c00 = r0 + xc0 * CIN;  g.c01 = r0 + xc1 * CIN;
    g.c10 = r1 + xc0 * CIN;  g.c11 = r1 + xc1 * CIN;
    return g;
}

// Fused kernel: one block per (n, ho); n = bid&7 (XCD-local). 512 threads = 8 waves.
__global__ __launch_bounds__(512, 2) void fused_main(
        const float* __restrict__ offs, const unsigned short* __restrict__ xt,
        const unsigned short* __restrict__ wt, float* __restrict__ out) {
    __shared__ __attribute__((aligned(16))) unsigned short samp[2][64][SROW];  // 34,816 B

    int b = blockIdx.x;
    int n = b & 7, ho = b >> 3;
    int t = threadIdx.x;
    int lane = t & 63, wv = t >> 6;
    int lm = lane & 15, lq = lane >> 4;

    // shared thread map for both phases: pos = t>>3 (0..63), 16-ch chunk = t&7
    int pos = t >> 3;
    int cb  = (t & 7) << 4;

    // ---------------- phase A: sample all 9 taps -> stash (regs; no barriers) --------
    const float* offp = offs + (size_t)(n * 2 * KK) * H * W + (size_t)ho * W + pos;
    const unsigned short* xb = xt + (size_t)n * H * W * CIN + cb;

    // v17 tweak: hoist ALL 18 offset loads -- issue back-to-back before any gather
    float dyv[KK], dxv[KK];
    #pragma unroll
    for (int tap = 0; tap < KK; ++tap) {
        dyv[tap] = offp[(size_t)(2 * tap) * H * W];
        dxv[tap] = offp[(size_t)(2 * tap + 1) * H * W];
    }

    unsigned stash[KK][8];                    // 72 VGPR, statically indexed (rule #20)
    #pragma unroll
    for (int tap = 0; tap < KK; ++tap) {
        GatherCtx g = gather_setup(dyv[tap], dxv[tap], ho, pos, tap, xb);
        uint4 gv[8];
        #pragma unroll
        for (int j = 0; j < 2; ++j) {
            gv[4*j+0] = *(const uint4*)(g.c00 + 8*j);
            gv[4*j+1] = *(const uint4*)(g.c01 + 8*j);
            gv[4*j+2] = *(const uint4*)(g.c10 + 8*j);
            gv[4*j+3] = *(const uint4*)(g.c11 + 8*j);
        }
        #pragma unroll
        for (int j = 0; j < 2; ++j) {
            const unsigned* a0 = (const unsigned*)&gv[4*j+0];
            const unsigned* a1 = (const unsigned*)&gv[4*j+1];
            const unsigned* a2 = (const unsigned*)&gv[4*j+2];
            const unsigned* a3 = (const unsigned*)&gv[4*j+3];
            #pragma unroll
            for (int i = 0; i < 4; ++i) {
                float v0 = g.w00*lo_f(a0[i]) + g.w01*lo_f(a1[i]) + g.w10*lo_f(a2[i]) + g.w11*lo_f(a3[i]);
                float v1 = g.w00*hi_f(a0[i]) + g.w01*hi_f(a1[i]) + g.w10*hi_f(a2[i]) + g.w11*hi_f(a3[i]);
                stash[tap][4*j+i] = cvt_pk_bf16(v0, v1);
            }
        }
    }

    // ---------------- phase B: GEMM over taps (8 waves, wave = 64 pos x 16 co) --------
    f32x4 acc[4];
    #pragma unroll
    for (int mt = 0; mt < 4; ++mt) acc[mt] = f32x4{0.f, 0.f, 0.f, 0.f};

    int slot = (lm << 2) + lq;
    // wave wv covers co block wv*16: wt2 base (tap*8 + wv)*2048 + slot*8; frag ct at +ct*512
    const unsigned short* wvbase = wt + ((size_t)wv << 11) + (slot << 3);

    // prologue: stage tap 0 from regs
    {
        unsigned short* ld = &samp[0][pos][cb];
        *(uint4*)(ld)     = make_uint4(stash[0][0], stash[0][1], stash[0][2], stash[0][3]);
        *(uint4*)(ld + 8) = make_uint4(stash[0][4], stash[0][5], stash[0][6], stash[0][7]);
    }
    __syncthreads();

    #pragma unroll
    for (int tap = 0; tap < KK; ++tap) {
        if (tap < KK - 1) {                   // stage tap+1 into the other buffer
            unsigned short* ld = &samp[(tap + 1) & 1][pos][cb];
            *(uint4*)(ld)     = make_uint4(stash[tap+1][0], stash[tap+1][1],
                                           stash[tap+1][2], stash[tap+1][3]);
            *(uint4*)(ld + 8) = make_uint4(stash[tap+1][4], stash[tap+1][5],
                                           stash[tap+1][6], stash[tap+1][7]);
        }
        // B-frags for this tap (verified wt2 layout), 4 x b128 per wave-lane
        const unsigned short* wkb = wvbase + ((size_t)(tap << 3) << 11);
        bf16x8 bW[4];
        #pragma unroll
        for (int ct = 0; ct < 4; ++ct)
            bW[ct] = *(const bf16x8*)(wkb + (ct << 9));

        __builtin_amdgcn_s_setprio(1);
        #pragma unroll
        for (int ct = 0; ct < 4; ++ct) {
            bf16x8 a[4];
            #pragma unroll
            for (int mt = 0; mt < 4; ++mt)
                a[mt] = *(const bf16x8*)&samp[tap & 1][lm + (mt << 4)][(ct << 5) + (lq << 3)];
            #pragma unroll
            for (int mt = 0; mt < 4; ++mt)
                acc[mt] = __builtin_amdgcn_mfma_f32_16x16x32_bf16(a[mt], bW[ct], acc[mt], 0, 0, 0);
        }
        __builtin_amdgcn_s_setprio(0);
        __syncthreads();
    }

    // epilogue: D[m = mt*16 + lq*4 + j][col = lm] -> out[n][co][ho][wo], float4 over wo
    int co = (wv << 4) + lm;
    #pragma unroll
    for (int mt = 0; mt < 4; ++mt) {
        int wob = (mt << 4) + (lq << 2);
        *(f32x4*)(out + (((size_t)(n * COUT + co) * H + ho) * W + wob)) = acc[mt];
    }
}

extern "C" void kernel_launch(void* const* d_in, const int* in_sizes, int n_in,
                              void* d_out, int out_size, void* d_ws, size_t ws_size,
                              hipStream_t stream) {
    const float* x      = (const float*)d_in[0];   // (8,128,64,64)
    const float* offset = (const float*)d_in[1];   // (8,18,64,64)
    const float* weight = (const float*)d_in[2];   // (128,128,3,3)
    float* out = (float*)d_out;

    unsigned short* xt = (unsigned short*)d_ws;                                  // 8 MB
    unsigned short* wt = (unsigned short*)((char*)d_ws + 8388608);               // 288 KB

    int wblocks = (KK * COUT * CIN + 255) / 256;   // 576
    hipLaunchKernelGGL(prep_all, dim3(NB * H + wblocks), dim3(256), 0, stream,
                       x, weight, xt, wt);
    hipLaunchKernelGGL(fused_main, dim3(NB * H), dim3(512), 0, stream,
                       offset, xt, wt, out);
}

// Round 17
// 102.329 us; speedup vs baseline: 1.5784x; 1.0482x over previous
//
#include <hip/hip_runtime.h>

// Deformable conv (K=3, stride=1, pad=1, dil=1), N=8, Cin=Cout=128, H=W=64.
// v18 == v11 EXACT (best measured: 102.7us total). Locked in after 17 structural
//   variants: barrier restructures, flag sync, asm pinning, kernel splits,
//   all-taps-LDS, occupancy up/down, cooperative mega-kernel all measured equal or
//   worse; remaining deltas are within run noise (+-5us).
//   Structure:
//   - prep_all: x NCHW fp32 -> xt NHWC bf16 (LDS-tiled transpose, rotate-swizzled,
//     XCD-local n=b&7) + weight -> wt2 fragment-contiguous bf16 (verified layout).
//   - fused_main (one block per (n,ho), 512 thr, 1 block/CU):
//     phase A: barrier-free 9-tap C++ gather chain (compiler-pipelined) ->
//       stash[9][8] regs (72 VGPR, statically indexed);
//     phase B: 8 waves, wave = 64 pos x 16 co; dbuf LDS samp[2][64][SROW]=34.8KB;
//       one barrier/tap; B-frags via verified wt2 path; setprio(1) around MFMA;
//       verified D-layout epilogue.
// ws: xt 8MB @0; wt2 288KB @8388608. Fully rewritten each launch.

#define H  64
#define W  64
#define CIN 128
#define COUT 128
#define NB 8
#define KK 9
#define SROW (CIN + 8)

typedef short bf16x8 __attribute__((ext_vector_type(8)));
typedef float f32x4  __attribute__((ext_vector_type(4)));

__device__ __forceinline__ unsigned short f2bf(float f) {
    unsigned u = __builtin_bit_cast(unsigned, f);
    u += 0x7FFFu + ((u >> 16) & 1u);          // round-nearest-even
    return (unsigned short)(u >> 16);
}
__device__ __forceinline__ unsigned cvt_pk_bf16(float lo, float hi) {
    unsigned r;
    asm("v_cvt_pk_bf16_f32 %0, %1, %2" : "=v"(r) : "v"(lo), "v"(hi));
    return r;                                  // low16 = bf16(lo), high16 = bf16(hi), RNE
}
__device__ __forceinline__ float lo_f(unsigned u) { return __builtin_bit_cast(float, u << 16); }
__device__ __forceinline__ float hi_f(unsigned u) { return __builtin_bit_cast(float, u & 0xFFFF0000u); }

// Merged prep: blocks [0, NB*H) transpose x (NCHW fp32 -> NHWC bf16), XCD-local (n = b&7);
// blocks [NB*H, NB*H+576): weight fp32 [co][c][kk] -> wt2 fragment-contiguous bf16:
//   wt2 flat idx = ((((kk*4 + c4)*2 + nt)*4 + ct)*64 + lm*4 + lq)*8 + e
//   where co = c4*32 + nt*16 + lm, ch = ct*32 + lq*8 + e.   [verified rounds 6-16]
__global__ void prep_all(const float* __restrict__ x, const float* __restrict__ w,
                         unsigned short* __restrict__ xt, unsigned short* __restrict__ wt) {
    int b = blockIdx.x;
    int t = threadIdx.x;
    if (b >= NB * H) {                        // ---- weight part ----
        int idx = (b - NB * H) * 256 + t;
        if (idx < KK * COUT * CIN) {
            int e  = idx & 7;
            int lq = (idx >> 3) & 3;
            int lm = (idx >> 5) & 15;
            int ct = (idx >> 9) & 3;
            int nt = (idx >> 11) & 1;
            int c4 = (idx >> 12) & 3;
            int kk = idx >> 14;
            int co = (c4 << 5) + (nt << 4) + lm;
            int ch = (ct << 5) + (lq << 3) + e;
            wt[idx] = f2bf(w[(co * CIN + ch) * KK + kk]);
        }
        return;
    }
    // ---- x-transpose part: one (n,y) row per block; n = b&7 matches XCD map ----
    __shared__ float tile[CIN][W + 4];
    int n = b & 7, y = b >> 3;
    const float* src = x + ((size_t)n * CIN * H + y) * W;
    #pragma unroll
    for (int it = 0; it < 8; ++it) {
        int idx = it * 256 + t;               // 0..2047 float4s
        int c  = idx >> 4;
        int x4 = (idx & 15) << 2;
        int xs = (x4 + ((c >> 5) << 4)) & 63; // rotate-swizzle per 32-ch group
        *(float4*)&tile[c][xs] = *(const float4*)(src + (size_t)c * H * W + x4);
    }
    __syncthreads();
    int xp = t >> 2;                          // x position 0..63
    int cbch = (t & 3) << 5;                  // channel base (32-ch chunk)
    int xr = (xp + ((cbch >> 5) << 4)) & 63;
    unsigned short* dst = xt + (((size_t)(n * H + y) * W + xp) * CIN + cbch);
    unsigned rr[16];
    #pragma unroll
    for (int i = 0; i < 16; ++i)
        rr[i] = cvt_pk_bf16(tile[cbch + 2 * i][xr], tile[cbch + 2 * i + 1][xr]);
    #pragma unroll
    for (int i = 0; i < 4; ++i)
        ((uint4*)dst)[i] = make_uint4(rr[4*i], rr[4*i+1], rr[4*i+2], rr[4*i+3]);
}

struct GatherCtx {
    const unsigned short *c00, *c01, *c10, *c11;
    float w00, w01, w10, w11;
};

__device__ __forceinline__ GatherCtx gather_setup(float dy, float dx, int ho, int wo, int kk,
                                                  const unsigned short* xbase) {
    GatherCtx g;
    float py = (float)(ho - 1 + kk / 3) + dy;
    float px = (float)(wo - 1 + kk % 3) + dx;
    float y0f = floorf(py), x0f = floorf(px);
    float wy1 = py - y0f, wx1 = px - x0f;
    float wy0 = 1.f - wy1, wx0 = 1.f - wx1;
    int y0 = (int)y0f, x0 = (int)x0f;
    int y1 = y0 + 1, x1 = x0 + 1;
    bool vy0 = (unsigned)y0 < (unsigned)H, vy1 = (unsigned)y1 < (unsigned)H;
    bool vx0 = (unsigned)x0 < (unsigned)W, vx1 = (unsigned)x1 < (unsigned)W;
    g.w00 = (vy0 && vx0) ? wy0 * wx0 : 0.f;
    g.w01 = (vy0 && vx1) ? wy0 * wx1 : 0.f;
    g.w10 = (vy1 && vx0) ? wy1 * wx0 : 0.f;
    g.w11 = (vy1 && vx1) ? wy1 * wx1 : 0.f;
    int yc0 = min(max(y0, 0), H - 1), yc1 = min(max(y1, 0), H - 1);
    int xc0 = min(max(x0, 0), W - 1), xc1 = min(max(x1, 0), W - 1);
    const unsigned short* r0 = xbase + (size_t)yc0 * W * CIN;
    const unsigned short* r1 = xbase + (size_t)yc1 * W * CIN;
    g.c00 = r0 + xc0 * CIN;  g.c01 = r0 + xc1 * CIN;
    g.c10 = r1 + xc0 * CIN;  g.c11 = r1 + xc1 * CIN;
    return g;
}

// Fused kernel: one block per (n, ho); n = bid&7 (XCD-local). 512 threads = 8 waves.
__global__ __launch_bounds__(512, 2) void fused_main(
        const float* __restrict__ offs, const unsigned short* __restrict__ xt,
        const unsigned short* __restrict__ wt, float* __restrict__ out) {
    __shared__ __attribute__((aligned(16))) unsigned short samp[2][64][SROW];  // 34,816 B

    int b = blockIdx.x;
    int n = b & 7, ho = b >> 3;
    int t = threadIdx.x;
    int lane = t & 63, wv = t >> 6;
    int lm = lane & 15, lq = lane >> 4;

    // shared thread map for both phases: pos = t>>3 (0..63), 16-ch chunk = t&7
    int pos = t >> 3;
    int cb  = (t & 7) << 4;

    // ---------------- phase A: sample all 9 taps -> stash (regs; no barriers) --------
    const float* offp = offs + (size_t)(n * 2 * KK) * H * W + (size_t)ho * W + pos;
    const unsigned short* xb = xt + (size_t)n * H * W * CIN + cb;

    unsigned stash[KK][8];                    // 72 VGPR, statically indexed (rule #20)
    #pragma unroll
    for (int tap = 0; tap < KK; ++tap) {
        float dy = offp[(size_t)(2 * tap) * H * W];
        float dx = offp[(size_t)(2 * tap + 1) * H * W];
        GatherCtx g = gather_setup(dy, dx, ho, pos, tap, xb);
        uint4 gv[8];
        #pragma unroll
        for (int j = 0; j < 2; ++j) {
            gv[4*j+0] = *(const uint4*)(g.c00 + 8*j);
            gv[4*j+1] = *(const uint4*)(g.c01 + 8*j);
            gv[4*j+2] = *(const uint4*)(g.c10 + 8*j);
            gv[4*j+3] = *(const uint4*)(g.c11 + 8*j);
        }
        #pragma unroll
        for (int j = 0; j < 2; ++j) {
            const unsigned* a0 = (const unsigned*)&gv[4*j+0];
            const unsigned* a1 = (const unsigned*)&gv[4*j+1];
            const unsigned* a2 = (const unsigned*)&gv[4*j+2];
            const unsigned* a3 = (const unsigned*)&gv[4*j+3];
            #pragma unroll
            for (int i = 0; i < 4; ++i) {
                float v0 = g.w00*lo_f(a0[i]) + g.w01*lo_f(a1[i]) + g.w10*lo_f(a2[i]) + g.w11*lo_f(a3[i]);
                float v1 = g.w00*hi_f(a0[i]) + g.w01*hi_f(a1[i]) + g.w10*hi_f(a2[i]) + g.w11*hi_f(a3[i]);
                stash[tap][4*j+i] = cvt_pk_bf16(v0, v1);
            }
        }
    }

    // ---------------- phase B: GEMM over taps (8 waves, wave = 64 pos x 16 co) --------
    f32x4 acc[4];
    #pragma unroll
    for (int mt = 0; mt < 4; ++mt) acc[mt] = f32x4{0.f, 0.f, 0.f, 0.f};

    int slot = (lm << 2) + lq;
    // wave wv covers co block wv*16: wt2 base (tap*8 + wv)*2048 + slot*8; frag ct at +ct*512
    const unsigned short* wvbase = wt + ((size_t)wv << 11) + (slot << 3);

    // prologue: stage tap 0 from regs
    {
        unsigned short* ld = &samp[0][pos][cb];
        *(uint4*)(ld)     = make_uint4(stash[0][0], stash[0][1], stash[0][2], stash[0][3]);
        *(uint4*)(ld + 8) = make_uint4(stash[0][4], stash[0][5], stash[0][6], stash[0][7]);
    }
    __syncthreads();

    #pragma unroll
    for (int tap = 0; tap < KK; ++tap) {
        if (tap < KK - 1) {                   // stage tap+1 into the other buffer
            unsigned short* ld = &samp[(tap + 1) & 1][pos][cb];
            *(uint4*)(ld)     = make_uint4(stash[tap+1][0], stash[tap+1][1],
                                           stash[tap+1][2], stash[tap+1][3]);
            *(uint4*)(ld + 8) = make_uint4(stash[tap+1][4], stash[tap+1][5],
                                           stash[tap+1][6], stash[tap+1][7]);
        }
        // B-frags for this tap (verified wt2 layout), 4 x b128 per wave-lane
        const unsigned short* wkb = wvbase + ((size_t)(tap << 3) << 11);
        bf16x8 bW[4];
        #pragma unroll
        for (int ct = 0; ct < 4; ++ct)
            bW[ct] = *(const bf16x8*)(wkb + (ct << 9));

        __builtin_amdgcn_s_setprio(1);
        #pragma unroll
        for (int ct = 0; ct < 4; ++ct) {
            bf16x8 a[4];
            #pragma unroll
            for (int mt = 0; mt < 4; ++mt)
                a[mt] = *(const bf16x8*)&samp[tap & 1][lm + (mt << 4)][(ct << 5) + (lq << 3)];
            #pragma unroll
            for (int mt = 0; mt < 4; ++mt)
                acc[mt] = __builtin_amdgcn_mfma_f32_16x16x32_bf16(a[mt], bW[ct], acc[mt], 0, 0, 0);
        }
        __builtin_amdgcn_s_setprio(0);
        __syncthreads();
    }

    // epilogue: D[m = mt*16 + lq*4 + j][col = lm] -> out[n][co][ho][wo], float4 over wo
    int co = (wv << 4) + lm;
    #pragma unroll
    for (int mt = 0; mt < 4; ++mt) {
        int wob = (mt << 4) + (lq << 2);
        *(f32x4*)(out + (((size_t)(n * COUT + co) * H + ho) * W + wob)) = acc[mt];
    }
}

extern "C" void kernel_launch(void* const* d_in, const int* in_sizes, int n_in,
                              void* d_out, int out_size, void* d_ws, size_t ws_size,
                              hipStream_t stream) {
    const float* x      = (const float*)d_in[0];   // (8,128,64,64)
    const float* offset = (const float*)d_in[1];   // (8,18,64,64)
    const float* weight = (const float*)d_in[2];   // (128,128,3,3)
    float* out = (float*)d_out;

    unsigned short* xt = (unsigned short*)d_ws;                                  // 8 MB
    unsigned short* wt = (unsigned short*)((char*)d_ws + 8388608);               // 288 KB

    int wblocks = (KK * COUT * CIN + 255) / 256;   // 576
    hipLaunchKernelGGL(prep_all, dim3(NB * H + wblocks), dim3(256), 0, stream,
                       x, weight, xt, wt);
    hipLaunchKernelGGL(fused_main, dim3(NB * H), dim3(512), 0, stream,
                       offset, xt, wt, out);
}